// Round 4
// baseline (5306.994 us; speedup 1.0000x reference)
//
#include <hip/hip_runtime.h>
#include <stdint.h>

#define D 512
#define VOCAB 256
#define NLAYER 12
#define BB 8
#define SS 8192

typedef __bf16 bf16x8 __attribute__((ext_vector_type(8)));
typedef float f32x4 __attribute__((ext_vector_type(4)));

__device__ __forceinline__ unsigned short f2bf(float f) {
  union { float f; uint32_t u; } c; c.f = f;
  uint32_t u = c.u;
  u += 0x7FFFu + ((u >> 16) & 1u);   // RNE
  return (unsigned short)(u >> 16);
}

__device__ __forceinline__ float ld_f32(const float* p) { return *p; }
__device__ __forceinline__ float ld_f32(const unsigned short* p) {
  union { uint32_t u; float f; } c; c.u = ((uint32_t)(*p)) << 16; return c.f;
}
__device__ __forceinline__ void st_f32(float* p, float v) { *p = v; }
__device__ __forceinline__ void st_f32(unsigned short* p, float v) { *p = f2bf(v); }

__device__ __forceinline__ float sigmoidf_(float x) {
  return __fdividef(1.0f, 1.0f + __expf(-x));
}

__device__ __forceinline__ float gfun(float h) {
  return h >= 0.0f ? h + 0.5f : sigmoidf_(h);
}

// ---------------- embedding gather: x[row,:] = emb[tok[row] & 255,:] ---------
__global__ __launch_bounds__(256) void k_gather(const int* __restrict__ toks,
                                                const float* __restrict__ emb,
                                                float* __restrict__ x) {
  int T = blockIdx.x * 256 + threadIdx.x;
  int row = T >> 6, lane = T & 63;
  int tok = toks[row] & (VOCAB - 1);
  const float4* s = (const float4*)(emb + (size_t)tok * D) + lane * 2;
  float4* d = (float4*)(x + (size_t)row * D) + lane * 2;
  d[0] = s[0];
  d[1] = s[1];
}

// ---------------- W (L,512,1024) fp32 -> Wt (L,1024,512) bf16 ----------------
__global__ __launch_bounds__(256) void k_convW(const float* __restrict__ W,
                                               unsigned short* __restrict__ Wt) {
  __shared__ float tile[32][33];
  int bid = blockIdx.x;
  int l = bid >> 9;
  int rem = bid & 511;
  int kt = rem >> 5, nt = rem & 31;
  int k0 = kt * 32, n0 = nt * 32;
  int tx = threadIdx.x & 31, ty = threadIdx.x >> 5;   // 32 x 8
  const float* Wl = W + (size_t)l * D * 2 * D;
  for (int i = 0; i < 4; i++) {
    int k = k0 + ty + 8 * i;
    tile[ty + 8 * i][tx] = Wl[(size_t)k * 1024 + n0 + tx];
  }
  __syncthreads();
  unsigned short* Wtl = Wt + (size_t)l * 1024 * D;
  for (int i = 0; i < 4; i++) {
    int n = n0 + ty + 8 * i;
    Wtl[(size_t)n * D + k0 + tx] = f2bf(tile[tx][ty + 8 * i]);
  }
}

// ---------------- emb fp32 -> bf16 (layout unchanged: V x D == N x K) --------
__global__ __launch_bounds__(256) void k_convEmb(const float* __restrict__ e,
                                                 unsigned short* __restrict__ o) {
  int t = blockIdx.x * 256 + threadIdx.x;   // one thread per 8 elements
  const float4* s = (const float4*)e + (size_t)t * 2;
  float4 a = s[0], b = s[1];
  uint32_t w0 = (uint32_t)f2bf(a.x) | ((uint32_t)f2bf(a.y) << 16);
  uint32_t w1 = (uint32_t)f2bf(a.z) | ((uint32_t)f2bf(a.w) << 16);
  uint32_t w2 = (uint32_t)f2bf(b.x) | ((uint32_t)f2bf(b.y) << 16);
  uint32_t w3 = (uint32_t)f2bf(b.z) | ((uint32_t)f2bf(b.w) << 16);
  uint4 r; r.x = w0; r.y = w1; r.z = w2; r.w = w3;
  ((uint4*)o)[t] = r;
}

// ---------------- LayerNorm fp32 -> bf16, one wave per row -------------------
__global__ __launch_bounds__(256) void k_ln(const float* __restrict__ x,
                                            const float* __restrict__ g,
                                            const float* __restrict__ b,
                                            unsigned short* __restrict__ o) {
  int wv = threadIdx.x >> 6, lane = threadIdx.x & 63;
  size_t row = (size_t)blockIdx.x * 4 + wv;
  const float4* xr = (const float4*)(x + row * D) + lane * 2;
  float4 v0 = xr[0], v1 = xr[1];
  float s = v0.x + v0.y + v0.z + v0.w + v1.x + v1.y + v1.z + v1.w;
  float ss = v0.x * v0.x + v0.y * v0.y + v0.z * v0.z + v0.w * v0.w +
             v1.x * v1.x + v1.y * v1.y + v1.z * v1.z + v1.w * v1.w;
  for (int m = 32; m; m >>= 1) {
    s += __shfl_xor(s, m, 64);
    ss += __shfl_xor(ss, m, 64);
  }
  float mu = s * (1.0f / 512.0f);
  float var = ss * (1.0f / 512.0f) - mu * mu;
  float rstd = rsqrtf(var + 1e-5f);
  const float4* gp = (const float4*)g + lane * 2;
  const float4* bp = (const float4*)b + lane * 2;
  float4 g0 = gp[0], g1 = gp[1], b0 = bp[0], b1 = bp[1];
  uint32_t w0 = (uint32_t)f2bf((v0.x - mu) * rstd * g0.x + b0.x) |
                ((uint32_t)f2bf((v0.y - mu) * rstd * g0.y + b0.y) << 16);
  uint32_t w1 = (uint32_t)f2bf((v0.z - mu) * rstd * g0.z + b0.z) |
                ((uint32_t)f2bf((v0.w - mu) * rstd * g0.w + b0.w) << 16);
  uint32_t w2 = (uint32_t)f2bf((v1.x - mu) * rstd * g1.x + b1.x) |
                ((uint32_t)f2bf((v1.y - mu) * rstd * g1.y + b1.y) << 16);
  uint32_t w3 = (uint32_t)f2bf((v1.z - mu) * rstd * g1.z + b1.z) |
                ((uint32_t)f2bf((v1.w - mu) * rstd * g1.w + b1.w) << 16);
  uint4 r; r.x = w0; r.y = w1; r.z = w2; r.w = w3;
  ((uint4*)(o + row * D))[lane] = r;
}

// ---------------- bf16 MFMA GEMM: C(MxN) = A(MxK=512) * Bt(NxK=512)^T --------
// 128x128 tile, 256 threads (4 waves), 16x16x32 bf16 MFMA. OT = float | ushort.
template <typename OT>
__global__ __launch_bounds__(256) void k_gemm(const unsigned short* __restrict__ A,
                                              const unsigned short* __restrict__ Bt,
                                              OT* __restrict__ C, int N) {
  __shared__ __align__(16) unsigned short As[128 * 72];
  __shared__ __align__(16) unsigned short Bs[128 * 72];
  const int tid = threadIdx.x;
  const int lane = tid & 63;
  const int wave = tid >> 6;
  const int m0 = blockIdx.y * 128;
  const int n0 = blockIdx.x * 128;
  const int wr = (wave >> 1) * 64;
  const int wc = (wave & 1) * 64;
  f32x4 acc[4][4] = {};
  const int ldr = tid >> 3;        // 0..31
  const int ldc = (tid & 7) * 8;   // 0..56 step 8
  const int qm = lane & 15;
  const int qko = (lane >> 4) * 8;
  for (int k0 = 0; k0 < 512; k0 += 64) {
    for (int i = 0; i < 4; i++) {
      int r = ldr + 32 * i;
      *(uint4*)(&As[r * 72 + ldc]) = *(const uint4*)(A + (size_t)(m0 + r) * 512 + k0 + ldc);
      *(uint4*)(&Bs[r * 72 + ldc]) = *(const uint4*)(Bt + (size_t)(n0 + r) * 512 + k0 + ldc);
    }
    __syncthreads();
    for (int ks = 0; ks < 2; ks++) {
      bf16x8 af[4], bfr[4];
      for (int i = 0; i < 4; i++) {
        af[i] = *(const bf16x8*)(&As[(wr + i * 16 + qm) * 72 + ks * 32 + qko]);
        bfr[i] = *(const bf16x8*)(&Bs[(wc + i * 16 + qm) * 72 + ks * 32 + qko]);
      }
      for (int i = 0; i < 4; i++)
        for (int j = 0; j < 4; j++)
          acc[i][j] = __builtin_amdgcn_mfma_f32_16x16x32_bf16(af[i], bfr[j], acc[i][j], 0, 0, 0);
    }
    __syncthreads();
  }
  const int col = lane & 15;
  const int rq = (lane >> 4) * 4;
  for (int i = 0; i < 4; i++)
    for (int j = 0; j < 4; j++)
      for (int r = 0; r < 4; r++)
        st_f32(&C[(size_t)(m0 + wr + i * 16 + rq + r) * N + (n0 + wc + j * 16 + col)],
               acc[i][j][r]);
}

// ---------------- scan phase 1: per-(b,chunk,d) summary (P = prod f, Q) ------
// hg layout: (b*S + s)*1024 + d (hidden) / +512+d (gate); HT = float | ushort
template <typename HT>
__global__ __launch_bounds__(256) void k_scan1(const HT* __restrict__ hg,
                                               float* __restrict__ P,
                                               float* __restrict__ Q) {
  int T = blockIdx.x * 256 + threadIdx.x;  // ((b*64)+c)*512 + d
  int d = T & 511;
  int bc = T >> 9;
  int c = bc & 63;
  int b = bc >> 6;
  const HT* base = hg + ((size_t)b * SS + c * 128) * 1024 + d;
  float p = 1.f, q = 0.f;
  for (int s = 0; s < 128; s++) {
    float hd = ld_f32(base + (size_t)s * 1024);
    float gt = ld_f32(base + (size_t)s * 1024 + 512);
    float f = sigmoidf_(-gt);
    float v = sigmoidf_(gt) * gfun(hd);
    p *= f;
    q = f * q + v;
  }
  P[T] = p;
  Q[T] = q;
}

// ---------------- scan phase 2: prefix over 64 chunks per (b,d) --------------
__global__ __launch_bounds__(256) void k_scan2(const float* __restrict__ P,
                                               const float* __restrict__ Q,
                                               float* __restrict__ Hs) {
  int T = blockIdx.x * 256 + threadIdx.x;  // b*512 + d
  int d = T & 511;
  int b = T >> 9;
  float h = 0.f;
  for (int c = 0; c < 64; c++) {
    size_t i = ((size_t)b * 64 + c) * 512 + d;
    Hs[i] = h;
    h = P[i] * h + Q[i];
  }
}

// ---------------- scan phase 3: apply + residual add into x ------------------
template <typename HT>
__global__ __launch_bounds__(256) void k_scan3(const HT* __restrict__ hg,
                                               const float* __restrict__ Hs,
                                               float* __restrict__ x) {
  int T = blockIdx.x * 256 + threadIdx.x;
  int d = T & 511;
  int bc = T >> 9;
  int c = bc & 63;
  int b = bc >> 6;
  const HT* base = hg + ((size_t)b * SS + c * 128) * 1024 + d;
  float* xb = x + ((size_t)b * SS + c * 128) * 512 + d;
  float h = Hs[T];
  for (int s = 0; s < 128; s++) {
    float hd = ld_f32(base + (size_t)s * 1024);
    float gt = ld_f32(base + (size_t)s * 1024 + 512);
    float f = sigmoidf_(-gt);
    float v = sigmoidf_(gt) * gfun(hd);
    h = f * h + v;
    xb[(size_t)s * 512] += h;
  }
}

extern "C" void kernel_launch(void* const* d_in, const int* in_sizes, int n_in,
                              void* d_out, int out_size, void* d_ws, size_t ws_size,
                              hipStream_t stream) {
  const int* toks = (const int*)d_in[0];
  const float* emb = (const float*)d_in[1];
  const float* ln_g = (const float*)d_in[2];
  const float* ln_b = (const float*)d_in[3];
  const float* W = (const float*)d_in[4];
  const float* norm_g = (const float*)d_in[5];
  const float* norm_b = (const float*)d_in[6];
  float* out = (float*)d_out;   // fp32 logits (reference output dtype)

  // Batches are independent end-to-end. Pick the largest batch-group GB (and
  // fp32-vs-bf16 hg, preferring fp32 for accuracy) that fits ws_size.
  // ws_size is constant across calls -> branch is graph-capture safe.
  const struct { int gb; int f32; } prefs[8] = {
      {8, 1}, {4, 1}, {2, 1}, {1, 1}, {8, 0}, {4, 0}, {2, 0}, {1, 0}};
  int GB = 1, F32HG = 0;
  for (int i = 0; i < 8; i++) {
    size_t MGv = (size_t)prefs[i].gb * SS;
    size_t hgB = prefs[i].f32 ? 4096 : 2048;           // bytes per row for hg
    size_t need = MGv * 2048 + MGv * hgB + MGv * 1024  // x + hg + hbf
                  + 12582912 + 262144                  // Wt + ebf
                  + (size_t)prefs[i].gb * 393216;      // P,Q,Hs
    if (need <= ws_size) { GB = prefs[i].gb; F32HG = prefs[i].f32; break; }
  }
  const int MG = GB * SS;   // rows per group

  char* p = (char*)d_ws;
  float* x = (float*)p;                     p += (size_t)MG * 2048;
  void* hgv = (void*)p;                     p += (size_t)MG * (F32HG ? 4096 : 2048);
  unsigned short* hbf = (unsigned short*)p; p += (size_t)MG * 1024;
  unsigned short* Wt = (unsigned short*)p;  p += 12582912;
  unsigned short* ebf = (unsigned short*)p; p += 262144;
  float* P = (float*)p;                     p += (size_t)GB * 131072;
  float* Q = (float*)p;                     p += (size_t)GB * 131072;
  float* Hs = (float*)p;

  k_convW<<<NLAYER * 512, 256, 0, stream>>>(W, Wt);
  k_convEmb<<<64, 256, 0, stream>>>(emb, ebf);

  for (int g = 0; g < BB / GB; g++) {
    const int* tg = toks + (size_t)g * MG;
    float* outg = out + (size_t)g * MG * VOCAB;

    k_gather<<<MG / 4, 256, 0, stream>>>(tg, emb, x);
    for (int l = 0; l < NLAYER; l++) {
      k_ln<<<MG / 4, 256, 0, stream>>>(x, ln_g + l * D, ln_b + l * D, hbf);
      if (F32HG) {
        float* hg = (float*)hgv;
        k_gemm<float><<<dim3(8, MG / 128), 256, 0, stream>>>(hbf, Wt + (size_t)l * 1024 * D, hg, 1024);
        k_scan1<float><<<GB * 128, 256, 0, stream>>>(hg, P, Q);
        k_scan2<<<GB * 2, 256, 0, stream>>>(P, Q, Hs);
        k_scan3<float><<<GB * 128, 256, 0, stream>>>(hg, Hs, x);
      } else {
        unsigned short* hg = (unsigned short*)hgv;
        k_gemm<unsigned short><<<dim3(8, MG / 128), 256, 0, stream>>>(hbf, Wt + (size_t)l * 1024 * D, hg, 1024);
        k_scan1<unsigned short><<<GB * 128, 256, 0, stream>>>(hg, P, Q);
        k_scan2<<<GB * 2, 256, 0, stream>>>(P, Q, Hs);
        k_scan3<unsigned short><<<GB * 128, 256, 0, stream>>>(hg, Hs, x);
      }
    }
    k_ln<<<MG / 4, 256, 0, stream>>>(x, norm_g, norm_b, hbf);
    k_gemm<float><<<dim3(2, MG / 128), 256, 0, stream>>>(hbf, ebf, outg, VOCAB);
  }
}

// Round 5
// 4524.890 us; speedup vs baseline: 1.1728x; 1.1728x over previous
//
#include <hip/hip_runtime.h>
#include <stdint.h>

#define D 512
#define VOCAB 256
#define NLAYER 12
#define BB 8
#define SS 8192

typedef __bf16 bf16x8 __attribute__((ext_vector_type(8)));
typedef float f32x4 __attribute__((ext_vector_type(4)));

__device__ __forceinline__ unsigned short f2bf(float f) {
  union { float f; uint32_t u; } c; c.f = f;
  uint32_t u = c.u;
  u += 0x7FFFu + ((u >> 16) & 1u);   // RNE
  return (unsigned short)(u >> 16);
}

__device__ __forceinline__ float bf2f(unsigned short v) {
  union { uint32_t u; float f; } c; c.u = ((uint32_t)v) << 16; return c.f;
}

__device__ __forceinline__ void st_f32(float* p, float v) { *p = v; }
__device__ __forceinline__ void st_f32(unsigned short* p, float v) { *p = f2bf(v); }

__device__ __forceinline__ float sigmoidf_(float x) {
  return __fdividef(1.0f, 1.0f + __expf(-x));
}

__device__ __forceinline__ float gfun(float h) {
  return h >= 0.0f ? h + 0.5f : sigmoidf_(h);
}

// async global->LDS, 16B per lane; LDS dest = uniform base + lane*16
__device__ __forceinline__ void gl_lds16(const unsigned short* g, unsigned short* l) {
  __builtin_amdgcn_global_load_lds((const __attribute__((address_space(1))) void*)(const void*)g,
                                   (__attribute__((address_space(3))) void*)(void*)l, 16, 0, 0);
}

// ---------------- embedding gather: x[row,:] = emb[tok[row] & 255,:] ---------
__global__ __launch_bounds__(256) void k_gather(const int* __restrict__ toks,
                                                const float* __restrict__ emb,
                                                float* __restrict__ x) {
  int T = blockIdx.x * 256 + threadIdx.x;
  int row = T >> 6, lane = T & 63;
  int tok = toks[row] & (VOCAB - 1);
  const float4* s = (const float4*)(emb + (size_t)tok * D) + lane * 2;
  float4* d = (float4*)(x + (size_t)row * D) + lane * 2;
  d[0] = s[0];
  d[1] = s[1];
}

// ---------------- W (L,512,1024) fp32 -> Wt (L,1024,512) bf16 ----------------
__global__ __launch_bounds__(256) void k_convW(const float* __restrict__ W,
                                               unsigned short* __restrict__ Wt) {
  __shared__ float tile[32][33];
  int bid = blockIdx.x;
  int l = bid >> 9;
  int rem = bid & 511;
  int kt = rem >> 5, nt = rem & 31;
  int k0 = kt * 32, n0 = nt * 32;
  int tx = threadIdx.x & 31, ty = threadIdx.x >> 5;   // 32 x 8
  const float* Wl = W + (size_t)l * D * 2 * D;
  for (int i = 0; i < 4; i++) {
    int k = k0 + ty + 8 * i;
    tile[ty + 8 * i][tx] = Wl[(size_t)k * 1024 + n0 + tx];
  }
  __syncthreads();
  unsigned short* Wtl = Wt + (size_t)l * 1024 * D;
  for (int i = 0; i < 4; i++) {
    int n = n0 + ty + 8 * i;
    Wtl[(size_t)n * D + k0 + tx] = f2bf(tile[tx][ty + 8 * i]);
  }
}

// ---------------- emb fp32 -> bf16 (layout unchanged: V x D == N x K) --------
__global__ __launch_bounds__(256) void k_convEmb(const float* __restrict__ e,
                                                 unsigned short* __restrict__ o) {
  int t = blockIdx.x * 256 + threadIdx.x;   // one thread per 8 elements
  const float4* s = (const float4*)e + (size_t)t * 2;
  float4 a = s[0], b = s[1];
  uint32_t w0 = (uint32_t)f2bf(a.x) | ((uint32_t)f2bf(a.y) << 16);
  uint32_t w1 = (uint32_t)f2bf(a.z) | ((uint32_t)f2bf(a.w) << 16);
  uint32_t w2 = (uint32_t)f2bf(b.x) | ((uint32_t)f2bf(b.y) << 16);
  uint32_t w3 = (uint32_t)f2bf(b.z) | ((uint32_t)f2bf(b.w) << 16);
  uint4 r; r.x = w0; r.y = w1; r.z = w2; r.w = w3;
  ((uint4*)o)[t] = r;
}

// ---------------- LayerNorm fp32 -> bf16, one wave per row -------------------
__global__ __launch_bounds__(256) void k_ln(const float* __restrict__ x,
                                            const float* __restrict__ g,
                                            const float* __restrict__ b,
                                            unsigned short* __restrict__ o) {
  int wv = threadIdx.x >> 6, lane = threadIdx.x & 63;
  size_t row = (size_t)blockIdx.x * 4 + wv;
  const float4* xr = (const float4*)(x + row * D) + lane * 2;
  float4 v0 = xr[0], v1 = xr[1];
  float s = v0.x + v0.y + v0.z + v0.w + v1.x + v1.y + v1.z + v1.w;
  float ss = v0.x * v0.x + v0.y * v0.y + v0.z * v0.z + v0.w * v0.w +
             v1.x * v1.x + v1.y * v1.y + v1.z * v1.z + v1.w * v1.w;
  for (int m = 32; m; m >>= 1) {
    s += __shfl_xor(s, m, 64);
    ss += __shfl_xor(ss, m, 64);
  }
  float mu = s * (1.0f / 512.0f);
  float var = ss * (1.0f / 512.0f) - mu * mu;
  float rstd = rsqrtf(var + 1e-5f);
  const float4* gp = (const float4*)g + lane * 2;
  const float4* bp = (const float4*)b + lane * 2;
  float4 g0 = gp[0], g1 = gp[1], b0 = bp[0], b1 = bp[1];
  uint32_t w0 = (uint32_t)f2bf((v0.x - mu) * rstd * g0.x + b0.x) |
                ((uint32_t)f2bf((v0.y - mu) * rstd * g0.y + b0.y) << 16);
  uint32_t w1 = (uint32_t)f2bf((v0.z - mu) * rstd * g0.z + b0.z) |
                ((uint32_t)f2bf((v0.w - mu) * rstd * g0.w + b0.w) << 16);
  uint32_t w2 = (uint32_t)f2bf((v1.x - mu) * rstd * g1.x + b1.x) |
                ((uint32_t)f2bf((v1.y - mu) * rstd * g1.y + b1.y) << 16);
  uint32_t w3 = (uint32_t)f2bf((v1.z - mu) * rstd * g1.z + b1.z) |
                ((uint32_t)f2bf((v1.w - mu) * rstd * g1.w + b1.w) << 16);
  uint4 r; r.x = w0; r.y = w1; r.z = w2; r.w = w3;
  ((uint4*)(o + row * D))[lane] = r;
}

// ---------------- bf16 MFMA GEMM: C(MxN) = A(MxK=512) * Bt(NxK=512)^T --------
// 128x128 tile, 256 threads (4 waves), 16x16x32 bf16 MFMA.
// Staging via global_load_lds (16B/lane) into unpadded LDS with XOR chunk
// swizzle (applied on the global-address side; LDS writes stay lane-linear as
// the HW requires). Fragment reads land <=2-way bank aliased (free, m136).
// 1D grid: mt = bid % MT so blocks sharing an A panel hit the same XCD.
template <typename OT>
__global__ __launch_bounds__(256) void k_gemm(const unsigned short* __restrict__ A,
                                              const unsigned short* __restrict__ Bt,
                                              OT* __restrict__ C, int N, int MT) {
  __shared__ __align__(16) unsigned short As[128 * 64];
  __shared__ __align__(16) unsigned short Bs[128 * 64];
  const int tid = threadIdx.x;
  const int lane = tid & 63;
  const int wave = tid >> 6;
  const int bid = blockIdx.x;
  const int mt = bid % MT;
  const int nt = bid / MT;
  const int m0 = mt * 128, n0 = nt * 128;
  const int wr = (wave >> 1) * 64;
  const int wc = (wave & 1) * 64;
  // staging: wave w covers rows [w*32, w*32+32), 4 iters of 8 rows.
  // lane i -> row lrow=i>>3, chunk pos i&7 holds global chunk (i&7)^lrow.
  const int lrow = lane >> 3;
  const int lcs = ((lane & 7) ^ lrow) * 8;   // swizzled global col (elems)
  const unsigned short* Ag = A + (size_t)(m0 + wave * 32 + lrow) * 512 + lcs;
  const unsigned short* Bg = Bt + (size_t)(n0 + wave * 32 + lrow) * 512 + lcs;
  unsigned short* Al = As + wave * 32 * 64;
  unsigned short* Bl = Bs + wave * 32 * 64;
  const int qm = lane & 15;
  const int hi = lane >> 4;   // 0..3
  f32x4 acc[4][4] = {};
  for (int k0 = 0; k0 < 512; k0 += 64) {
    for (int j = 0; j < 4; j++)
      gl_lds16(Ag + k0 + (size_t)j * 8 * 512, Al + j * 512);
    for (int j = 0; j < 4; j++)
      gl_lds16(Bg + k0 + (size_t)j * 8 * 512, Bl + j * 512);
    __syncthreads();
    for (int ks = 0; ks < 2; ks++) {
      bf16x8 af[4], bfr[4];
      const int sw = ((ks * 4 + hi) ^ (qm & 7)) * 8;   // swizzled chunk (elems)
      for (int i = 0; i < 4; i++) {
        af[i] = *(const bf16x8*)(&As[(wr + i * 16 + qm) * 64 + sw]);
        bfr[i] = *(const bf16x8*)(&Bs[(wc + i * 16 + qm) * 64 + sw]);
      }
      for (int i = 0; i < 4; i++)
        for (int j = 0; j < 4; j++)
          acc[i][j] = __builtin_amdgcn_mfma_f32_16x16x32_bf16(af[i], bfr[j], acc[i][j], 0, 0, 0);
    }
    __syncthreads();
  }
  const int col = lane & 15;
  const int rq = (lane >> 4) * 4;
  for (int i = 0; i < 4; i++)
    for (int j = 0; j < 4; j++)
      for (int r = 0; r < 4; r++)
        st_f32(&C[(size_t)(m0 + wr + i * 16 + rq + r) * N + (n0 + wc + j * 16 + col)],
               acc[i][j][r]);
}

// ---------------- scan phase 1: per-(b,chunk,d) summary (P = prod f, Q) ------
// hg (bf16): (b*S + s)*1024 + d (hidden) / +512+d (gate)
__global__ __launch_bounds__(256) void k_scan1(const unsigned short* __restrict__ hg,
                                               float* __restrict__ P,
                                               float* __restrict__ Q) {
  int T = blockIdx.x * 256 + threadIdx.x;  // ((b*64)+c)*512 + d
  int d = T & 511;
  int bc = T >> 9;
  int c = bc & 63;
  int b = bc >> 6;
  const unsigned short* base = hg + ((size_t)b * SS + c * 128) * 1024 + d;
  float p = 1.f, q = 0.f;
  for (int s = 0; s < 128; s++) {
    float hd = bf2f(base[(size_t)s * 1024]);
    float gt = bf2f(base[(size_t)s * 1024 + 512]);
    float f = sigmoidf_(-gt);
    float v = sigmoidf_(gt) * gfun(hd);
    p *= f;
    q = f * q + v;
  }
  P[T] = p;
  Q[T] = q;
}

// ---------------- scan phase 2: prefix over 64 chunks per (b,d) --------------
__global__ __launch_bounds__(256) void k_scan2(const float* __restrict__ P,
                                               const float* __restrict__ Q,
                                               float* __restrict__ Hs) {
  int T = blockIdx.x * 256 + threadIdx.x;  // b*512 + d
  int d = T & 511;
  int b = T >> 9;
  float h = 0.f;
  for (int c = 0; c < 64; c++) {
    size_t i = ((size_t)b * 64 + c) * 512 + d;
    Hs[i] = h;
    h = P[i] * h + Q[i];
  }
}

// ---------------- scan phase 3: apply + residual add into x ------------------
__global__ __launch_bounds__(256) void k_scan3(const unsigned short* __restrict__ hg,
                                               const float* __restrict__ Hs,
                                               float* __restrict__ x) {
  int T = blockIdx.x * 256 + threadIdx.x;
  int d = T & 511;
  int bc = T >> 9;
  int c = bc & 63;
  int b = bc >> 6;
  const unsigned short* base = hg + ((size_t)b * SS + c * 128) * 1024 + d;
  float* xb = x + ((size_t)b * SS + c * 128) * 512 + d;
  float h = Hs[T];
  for (int s = 0; s < 128; s++) {
    float hd = bf2f(base[(size_t)s * 1024]);
    float gt = bf2f(base[(size_t)s * 1024 + 512]);
    float f = sigmoidf_(-gt);
    float v = sigmoidf_(gt) * gfun(hd);
    h = f * h + v;
    xb[(size_t)s * 512] += h;
  }
}

extern "C" void kernel_launch(void* const* d_in, const int* in_sizes, int n_in,
                              void* d_out, int out_size, void* d_ws, size_t ws_size,
                              hipStream_t stream) {
  const int* toks = (const int*)d_in[0];
  const float* emb = (const float*)d_in[1];
  const float* ln_g = (const float*)d_in[2];
  const float* ln_b = (const float*)d_in[3];
  const float* W = (const float*)d_in[4];
  const float* norm_g = (const float*)d_in[5];
  const float* norm_b = (const float*)d_in[6];
  float* out = (float*)d_out;   // fp32 logits

  // Batch-group ladder (bf16 hg): footprint = MG*5120 + ~13 MiB.
  // ws_size is constant across calls -> branch is graph-capture safe.
  const int gbs[4] = {8, 4, 2, 1};
  int GB = 1;
  for (int i = 0; i < 4; i++) {
    size_t MGv = (size_t)gbs[i] * SS;
    size_t need = MGv * 5120 + 12582912 + 262144 + (size_t)gbs[i] * 393216;
    if (need <= ws_size) { GB = gbs[i]; break; }
  }
  const int MG = GB * SS;      // rows per group
  const int MT = MG / 128;     // m-tiles (multiple of 8)

  char* p = (char*)d_ws;
  float* x = (float*)p;                     p += (size_t)MG * 2048;
  unsigned short* hg = (unsigned short*)p;  p += (size_t)MG * 2048;
  unsigned short* hbf = (unsigned short*)p; p += (size_t)MG * 1024;
  unsigned short* Wt = (unsigned short*)p;  p += 12582912;
  unsigned short* ebf = (unsigned short*)p; p += 262144;
  float* P = (float*)p;                     p += (size_t)GB * 131072;
  float* Q = (float*)p;                     p += (size_t)GB * 131072;
  float* Hs = (float*)p;

  k_convW<<<NLAYER * 512, 256, 0, stream>>>(W, Wt);
  k_convEmb<<<64, 256, 0, stream>>>(emb, ebf);

  for (int g = 0; g < BB / GB; g++) {
    const int* tg = toks + (size_t)g * MG;
    float* outg = out + (size_t)g * MG * VOCAB;

    k_gather<<<MG / 4, 256, 0, stream>>>(tg, emb, x);
    for (int l = 0; l < NLAYER; l++) {
      k_ln<<<MG / 4, 256, 0, stream>>>(x, ln_g + l * D, ln_b + l * D, hbf);
      k_gemm<unsigned short><<<8 * MT, 256, 0, stream>>>(hbf, Wt + (size_t)l * 1024 * D, hg, 1024, MT);
      k_scan1<<<GB * 128, 256, 0, stream>>>(hg, P, Q);
      k_scan2<<<GB * 2, 256, 0, stream>>>(P, Q, Hs);
      k_scan3<<<GB * 128, 256, 0, stream>>>(hg, Hs, x);
    }
    k_ln<<<MG / 4, 256, 0, stream>>>(x, norm_g, norm_b, hbf);
    k_gemm<float><<<2 * MT, 256, 0, stream>>>(hbf, ebf, outg, VOCAB, MT);
  }
}

// Round 6
// 3679.523 us; speedup vs baseline: 1.4423x; 1.2297x over previous
//
#include <hip/hip_runtime.h>
#include <stdint.h>

#define D 512
#define VOCAB 256
#define NLAYER 12
#define BB 8
#define SS 8192
#define CH 128          // scan chunks per sequence
#define SL (SS / CH)    // 64 steps per chunk

typedef __bf16 bf16x8 __attribute__((ext_vector_type(8)));
typedef float f32x4 __attribute__((ext_vector_type(4)));
typedef _Float16 half2_t __attribute__((ext_vector_type(2)));

__device__ __forceinline__ unsigned short f2bf(float f) {
  union { float f; uint32_t u; } c; c.f = f;
  uint32_t u = c.u;
  u += 0x7FFFu + ((u >> 16) & 1u);   // RNE
  return (unsigned short)(u >> 16);
}

__device__ __forceinline__ void st_f32(float* p, float v) { *p = v; }
__device__ __forceinline__ void st_f32(unsigned short* p, float v) { *p = f2bf(v); }

__device__ __forceinline__ float rcpf_(float x) { return __builtin_amdgcn_rcpf(x); }

// pack (f,v) as two fp16 in one uint32
__device__ __forceinline__ uint32_t pack_fv(float f, float v) {
  union { half2_t h; uint32_t u; } c;
  c.h.x = (_Float16)f;
  c.h.y = (_Float16)v;
  return c.u;
}

__device__ __forceinline__ void unpack_fv(uint32_t u, float& f, float& v) {
  union { uint32_t u; half2_t h; } c; c.u = u;
  f = (float)c.h.x;
  v = (float)c.h.y;
}

// async global->LDS, 16B per lane; LDS dest = uniform base + lane*16
__device__ __forceinline__ void gl_lds16(const unsigned short* g, unsigned short* l) {
  __builtin_amdgcn_global_load_lds((const __attribute__((address_space(1))) void*)(const void*)g,
                                   (__attribute__((address_space(3))) void*)(void*)l, 16, 0, 0);
}

// ---------------- embedding gather ------------------------------------------
__global__ __launch_bounds__(256) void k_gather(const int* __restrict__ toks,
                                                const float* __restrict__ emb,
                                                float* __restrict__ x) {
  int T = blockIdx.x * 256 + threadIdx.x;
  int row = T >> 6, lane = T & 63;
  int tok = toks[row] & (VOCAB - 1);
  const float4* s = (const float4*)(emb + (size_t)tok * D) + lane * 2;
  float4* d = (float4*)(x + (size_t)row * D) + lane * 2;
  d[0] = s[0];
  d[1] = s[1];
}

// ---------------- W (L,512,1024) fp32 -> Wt (L,1024,512) bf16 ----------------
__global__ __launch_bounds__(256) void k_convW(const float* __restrict__ W,
                                               unsigned short* __restrict__ Wt) {
  __shared__ float tile[32][33];
  int bid = blockIdx.x;
  int l = bid >> 9;
  int rem = bid & 511;
  int kt = rem >> 5, nt = rem & 31;
  int k0 = kt * 32, n0 = nt * 32;
  int tx = threadIdx.x & 31, ty = threadIdx.x >> 5;   // 32 x 8
  const float* Wl = W + (size_t)l * D * 2 * D;
  for (int i = 0; i < 4; i++) {
    int k = k0 + ty + 8 * i;
    tile[ty + 8 * i][tx] = Wl[(size_t)k * 1024 + n0 + tx];
  }
  __syncthreads();
  unsigned short* Wtl = Wt + (size_t)l * 1024 * D;
  for (int i = 0; i < 4; i++) {
    int n = n0 + ty + 8 * i;
    Wtl[(size_t)n * D + k0 + tx] = f2bf(tile[tx][ty + 8 * i]);
  }
}

// ---------------- emb fp32 -> bf16 ------------------------------------------
__global__ __launch_bounds__(256) void k_convEmb(const float* __restrict__ e,
                                                 unsigned short* __restrict__ o) {
  int t = blockIdx.x * 256 + threadIdx.x;
  const float4* s = (const float4*)e + (size_t)t * 2;
  float4 a = s[0], b = s[1];
  uint32_t w0 = (uint32_t)f2bf(a.x) | ((uint32_t)f2bf(a.y) << 16);
  uint32_t w1 = (uint32_t)f2bf(a.z) | ((uint32_t)f2bf(a.w) << 16);
  uint32_t w2 = (uint32_t)f2bf(b.x) | ((uint32_t)f2bf(b.y) << 16);
  uint32_t w3 = (uint32_t)f2bf(b.z) | ((uint32_t)f2bf(b.w) << 16);
  uint4 r; r.x = w0; r.y = w1; r.z = w2; r.w = w3;
  ((uint4*)o)[t] = r;
}

// ---------------- LayerNorm fp32 -> bf16, one wave per row -------------------
__global__ __launch_bounds__(256) void k_ln(const float* __restrict__ x,
                                            const float* __restrict__ g,
                                            const float* __restrict__ b,
                                            unsigned short* __restrict__ o) {
  int wv = threadIdx.x >> 6, lane = threadIdx.x & 63;
  size_t row = (size_t)blockIdx.x * 4 + wv;
  const float4* xr = (const float4*)(x + row * D) + lane * 2;
  float4 v0 = xr[0], v1 = xr[1];
  float s = v0.x + v0.y + v0.z + v0.w + v1.x + v1.y + v1.z + v1.w;
  float ss = v0.x * v0.x + v0.y * v0.y + v0.z * v0.z + v0.w * v0.w +
             v1.x * v1.x + v1.y * v1.y + v1.z * v1.z + v1.w * v1.w;
  for (int m = 32; m; m >>= 1) {
    s += __shfl_xor(s, m, 64);
    ss += __shfl_xor(ss, m, 64);
  }
  float mu = s * (1.0f / 512.0f);
  float var = ss * (1.0f / 512.0f) - mu * mu;
  float rstd = rsqrtf(var + 1e-5f);
  const float4* gp = (const float4*)g + lane * 2;
  const float4* bp = (const float4*)b + lane * 2;
  float4 g0 = gp[0], g1 = gp[1], b0 = bp[0], b1 = bp[1];
  uint32_t w0 = (uint32_t)f2bf((v0.x - mu) * rstd * g0.x + b0.x) |
                ((uint32_t)f2bf((v0.y - mu) * rstd * g0.y + b0.y) << 16);
  uint32_t w1 = (uint32_t)f2bf((v0.z - mu) * rstd * g0.z + b0.z) |
                ((uint32_t)f2bf((v0.w - mu) * rstd * g0.w + b0.w) << 16);
  uint32_t w2 = (uint32_t)f2bf((v1.x - mu) * rstd * g1.x + b1.x) |
                ((uint32_t)f2bf((v1.y - mu) * rstd * g1.y + b1.y) << 16);
  uint32_t w3 = (uint32_t)f2bf((v1.z - mu) * rstd * g1.z + b1.z) |
                ((uint32_t)f2bf((v1.w - mu) * rstd * g1.w + b1.w) << 16);
  uint4 r; r.x = w0; r.y = w1; r.z = w2; r.w = w3;
  ((uint4*)(o + row * D))[lane] = r;
}

// ---------------- fused GEMM + activation ------------------------------------
// Block nt in 0..3 computes hidden cols [nt*128, nt*128+128) AND the matching
// gate cols (+512), then writes packed fp16 (f,v) per element.
// A-panel shared by 4 blocks, all congruent mod 8 -> same XCD.
__global__ __launch_bounds__(256) void k_gemm_act(const unsigned short* __restrict__ A,
                                                  const unsigned short* __restrict__ Bt,
                                                  uint32_t* __restrict__ fv, int MT) {
  __shared__ __align__(16) unsigned short As[128 * 64];
  __shared__ __align__(16) unsigned short Bh[128 * 64];
  __shared__ __align__(16) unsigned short Bg[128 * 64];
  const int tid = threadIdx.x;
  const int lane = tid & 63;
  const int wave = tid >> 6;
  const int bid = blockIdx.x;
  const int mt = bid % MT;
  const int nt = bid / MT;
  const int m0 = mt * 128, n0 = nt * 128;
  const int wr = (wave >> 1) * 64;
  const int wc = (wave & 1) * 64;
  const int lrow = lane >> 3;
  const int lcs = ((lane & 7) ^ lrow) * 8;
  const unsigned short* Ag = A + (size_t)(m0 + wave * 32 + lrow) * 512 + lcs;
  const unsigned short* Bhg = Bt + (size_t)(n0 + wave * 32 + lrow) * 512 + lcs;
  const unsigned short* Bgg = Bt + (size_t)(512 + n0 + wave * 32 + lrow) * 512 + lcs;
  unsigned short* Al = As + wave * 32 * 64;
  unsigned short* Bhl = Bh + wave * 32 * 64;
  unsigned short* Bgl = Bg + wave * 32 * 64;
  const int qm = lane & 15;
  const int hi = lane >> 4;
  f32x4 ah[4][4] = {};
  f32x4 ag[4][4] = {};
  for (int k0 = 0; k0 < 512; k0 += 64) {
    for (int j = 0; j < 4; j++) gl_lds16(Ag + k0 + (size_t)j * 8 * 512, Al + j * 512);
    for (int j = 0; j < 4; j++) gl_lds16(Bhg + k0 + (size_t)j * 8 * 512, Bhl + j * 512);
    for (int j = 0; j < 4; j++) gl_lds16(Bgg + k0 + (size_t)j * 8 * 512, Bgl + j * 512);
    __syncthreads();
    for (int ks = 0; ks < 2; ks++) {
      const int sw = ((ks * 4 + hi) ^ (qm & 7)) * 8;
      bf16x8 af[4], bh[4], bg[4];
      for (int i = 0; i < 4; i++) {
        af[i] = *(const bf16x8*)(&As[(wr + i * 16 + qm) * 64 + sw]);
        bh[i] = *(const bf16x8*)(&Bh[(wc + i * 16 + qm) * 64 + sw]);
        bg[i] = *(const bf16x8*)(&Bg[(wc + i * 16 + qm) * 64 + sw]);
      }
      for (int i = 0; i < 4; i++)
        for (int j = 0; j < 4; j++) {
          ah[i][j] = __builtin_amdgcn_mfma_f32_16x16x32_bf16(af[i], bh[j], ah[i][j], 0, 0, 0);
          ag[i][j] = __builtin_amdgcn_mfma_f32_16x16x32_bf16(af[i], bg[j], ag[i][j], 0, 0, 0);
        }
    }
    __syncthreads();
  }
  const int col = lane & 15;
  const int rq = (lane >> 4) * 4;
  for (int i = 0; i < 4; i++)
    for (int j = 0; j < 4; j++)
      for (int r = 0; r < 4; r++) {
        float h = ah[i][j][r];
        float g = ag[i][j][r];
        // f = sigma(-g), sg = sigma(g) = 1 - f   (NaN-safe for any g)
        float e = __expf(g);
        float f = rcpf_(1.0f + e);
        float sg = 1.0f - f;
        float eh = __expf(-h);
        float gneg = rcpf_(1.0f + eh);        // sigma(h)
        float gf = h >= 0.0f ? h + 0.5f : gneg;
        float v = sg * gf;
        size_t row = (size_t)(m0 + wr + i * 16 + rq + r);
        fv[row * 512 + (n0 + wc + j * 16 + col)] = pack_fv(f, v);
      }
}

// ---------------- plain GEMM (logits): C = A(Mx512) * Bt(Nx512)^T ------------
template <typename OT>
__global__ __launch_bounds__(256) void k_gemm(const unsigned short* __restrict__ A,
                                              const unsigned short* __restrict__ Bt,
                                              OT* __restrict__ C, int N, int MT) {
  __shared__ __align__(16) unsigned short As[128 * 64];
  __shared__ __align__(16) unsigned short Bs[128 * 64];
  const int tid = threadIdx.x;
  const int lane = tid & 63;
  const int wave = tid >> 6;
  const int bid = blockIdx.x;
  const int mt = bid % MT;
  const int nt = bid / MT;
  const int m0 = mt * 128, n0 = nt * 128;
  const int wr = (wave >> 1) * 64;
  const int wc = (wave & 1) * 64;
  const int lrow = lane >> 3;
  const int lcs = ((lane & 7) ^ lrow) * 8;
  const unsigned short* Ag = A + (size_t)(m0 + wave * 32 + lrow) * 512 + lcs;
  const unsigned short* Bg = Bt + (size_t)(n0 + wave * 32 + lrow) * 512 + lcs;
  unsigned short* Al = As + wave * 32 * 64;
  unsigned short* Bl = Bs + wave * 32 * 64;
  const int qm = lane & 15;
  const int hi = lane >> 4;
  f32x4 acc[4][4] = {};
  for (int k0 = 0; k0 < 512; k0 += 64) {
    for (int j = 0; j < 4; j++) gl_lds16(Ag + k0 + (size_t)j * 8 * 512, Al + j * 512);
    for (int j = 0; j < 4; j++) gl_lds16(Bg + k0 + (size_t)j * 8 * 512, Bl + j * 512);
    __syncthreads();
    for (int ks = 0; ks < 2; ks++) {
      const int sw = ((ks * 4 + hi) ^ (qm & 7)) * 8;
      bf16x8 af[4], bfr[4];
      for (int i = 0; i < 4; i++) {
        af[i] = *(const bf16x8*)(&As[(wr + i * 16 + qm) * 64 + sw]);
        bfr[i] = *(const bf16x8*)(&Bs[(wc + i * 16 + qm) * 64 + sw]);
      }
      for (int i = 0; i < 4; i++)
        for (int j = 0; j < 4; j++)
          acc[i][j] = __builtin_amdgcn_mfma_f32_16x16x32_bf16(af[i], bfr[j], acc[i][j], 0, 0, 0);
    }
    __syncthreads();
  }
  const int col = lane & 15;
  const int rq = (lane >> 4) * 4;
  for (int i = 0; i < 4; i++)
    for (int j = 0; j < 4; j++)
      for (int r = 0; r < 4; r++)
        st_f32(&C[(size_t)(m0 + wr + i * 16 + rq + r) * N + (n0 + wc + j * 16 + col)],
               acc[i][j][r]);
}

// ---------------- scan phase 1: per-(b,chunk,d) (P = prod f, Q) --------------
__global__ __launch_bounds__(256) void k_scan1(const uint32_t* __restrict__ fv,
                                               float* __restrict__ P,
                                               float* __restrict__ Q) {
  int T = blockIdx.x * 256 + threadIdx.x;  // ((b*CH)+c)*512 + d
  int d = T & 511;
  int bc = T >> 9;
  int c = bc & (CH - 1);
  int b = bc >> 7;
  const uint32_t* base = fv + ((size_t)b * SS + c * SL) * 512 + d;
  float p = 1.f, q = 0.f;
  for (int s = 0; s < SL; s++) {
    float f, v;
    unpack_fv(base[(size_t)s * 512], f, v);
    p *= f;
    q = f * q + v;
  }
  P[T] = p;
  Q[T] = q;
}

// ---------------- scan phase 2: prefix over CH chunks per (b,d) --------------
__global__ __launch_bounds__(256) void k_scan2(const float* __restrict__ P,
                                               const float* __restrict__ Q,
                                               float* __restrict__ Hs) {
  int T = blockIdx.x * 256 + threadIdx.x;  // b*512 + d
  int d = T & 511;
  int b = T >> 9;
  float h = 0.f;
  for (int c = 0; c < CH; c++) {
    size_t i = ((size_t)b * CH + c) * 512 + d;
    Hs[i] = h;
    h = P[i] * h + Q[i];
  }
}

// ---------------- scan phase 3: apply + residual add into x ------------------
__global__ __launch_bounds__(256) void k_scan3(const uint32_t* __restrict__ fv,
                                               const float* __restrict__ Hs,
                                               float* __restrict__ x) {
  int T = blockIdx.x * 256 + threadIdx.x;
  int d = T & 511;
  int bc = T >> 9;
  int c = bc & (CH - 1);
  int b = bc >> 7;
  const uint32_t* base = fv + ((size_t)b * SS + c * SL) * 512 + d;
  float* xb = x + ((size_t)b * SS + c * SL) * 512 + d;
  float h = Hs[T];
  for (int s = 0; s < SL; s++) {
    float f, v;
    unpack_fv(base[(size_t)s * 512], f, v);
    h = f * h + v;
    xb[(size_t)s * 512] += h;
  }
}

extern "C" void kernel_launch(void* const* d_in, const int* in_sizes, int n_in,
                              void* d_out, int out_size, void* d_ws, size_t ws_size,
                              hipStream_t stream) {
  const int* toks = (const int*)d_in[0];
  const float* emb = (const float*)d_in[1];
  const float* ln_g = (const float*)d_in[2];
  const float* ln_b = (const float*)d_in[3];
  const float* W = (const float*)d_in[4];
  const float* norm_g = (const float*)d_in[5];
  const float* norm_b = (const float*)d_in[6];
  float* out = (float*)d_out;   // fp32 logits

  // Batch-group ladder: footprint = MG*5120 + 13 MiB + GB*0.75 MiB.
  const int gbs[4] = {8, 4, 2, 1};
  int GB = 1;
  for (int i = 0; i < 4; i++) {
    size_t MGv = (size_t)gbs[i] * SS;
    size_t need = MGv * 5120 + 12582912 + 262144 + (size_t)gbs[i] * 786432;
    if (need <= ws_size) { GB = gbs[i]; break; }
  }
  const int MG = GB * SS;      // rows per group
  const int MT = MG / 128;     // m-tiles (multiple of 8)

  char* p = (char*)d_ws;
  float* x = (float*)p;                     p += (size_t)MG * 2048;
  uint32_t* fv = (uint32_t*)p;              p += (size_t)MG * 2048;
  unsigned short* hbf = (unsigned short*)p; p += (size_t)MG * 1024;
  unsigned short* Wt = (unsigned short*)p;  p += 12582912;
  unsigned short* ebf = (unsigned short*)p; p += 262144;
  float* P = (float*)p;                     p += (size_t)GB * 262144;
  float* Q = (float*)p;                     p += (size_t)GB * 262144;
  float* Hs = (float*)p;

  k_convW<<<NLAYER * 512, 256, 0, stream>>>(W, Wt);
  k_convEmb<<<64, 256, 0, stream>>>(emb, ebf);

  for (int g = 0; g < BB / GB; g++) {
    const int* tg = toks + (size_t)g * MG;
    float* outg = out + (size_t)g * MG * VOCAB;

    k_gather<<<MG / 4, 256, 0, stream>>>(tg, emb, x);
    for (int l = 0; l < NLAYER; l++) {
      k_ln<<<MG / 4, 256, 0, stream>>>(x, ln_g + l * D, ln_b + l * D, hbf);
      k_gemm_act<<<4 * MT, 256, 0, stream>>>(hbf, Wt + (size_t)l * 1024 * D, fv, MT);
      k_scan1<<<GB * CH * 2, 256, 0, stream>>>(fv, P, Q);
      k_scan2<<<GB * 2, 256, 0, stream>>>(P, Q, Hs);
      k_scan3<<<GB * CH * 2, 256, 0, stream>>>(fv, Hs, x);
    }
    k_ln<<<MG / 4, 256, 0, stream>>>(x, norm_g, norm_b, hbf);
    k_gemm<float><<<2 * MT, 256, 0, stream>>>(hbf, ebf, outg, VOCAB, MT);
  }
}

// Round 7
// 3128.718 us; speedup vs baseline: 1.6962x; 1.1760x over previous
//
#include <hip/hip_runtime.h>
#include <stdint.h>

#define D 512
#define VOCAB 256
#define NLAYER 12
#define BB 8
#define SS 8192
#define CH 128          // scan chunks per sequence (SL=64)
#define SL 64

typedef __bf16 bf16x8 __attribute__((ext_vector_type(8)));
typedef float f32x4 __attribute__((ext_vector_type(4)));
typedef _Float16 half2_t __attribute__((ext_vector_type(2)));

__device__ __forceinline__ unsigned short f2bf(float f) {
  union { float f; uint32_t u; } c; c.f = f;
  uint32_t u = c.u;
  u += 0x7FFFu + ((u >> 16) & 1u);   // RNE
  return (unsigned short)(u >> 16);
}

__device__ __forceinline__ void st_f32(float* p, float v) { *p = v; }
__device__ __forceinline__ void st_f32(unsigned short* p, float v) { *p = f2bf(v); }

__device__ __forceinline__ float rcpf_(float x) { return __builtin_amdgcn_rcpf(x); }

__device__ __forceinline__ uint32_t pack_fv(float f, float v) {
  union { half2_t h; uint32_t u; } c;
  c.h.x = (_Float16)f;
  c.h.y = (_Float16)v;
  return c.u;
}

__device__ __forceinline__ void unpack_fv(uint32_t u, float& f, float& v) {
  union { uint32_t u; half2_t h; } c; c.u = u;
  f = (float)c.h.x;
  v = (float)c.h.y;
}

__device__ __forceinline__ void gl_lds16(const unsigned short* g, unsigned short* l) {
  __builtin_amdgcn_global_load_lds((const __attribute__((address_space(1))) void*)(const void*)g,
                                   (__attribute__((address_space(3))) void*)(void*)l, 16, 0, 0);
}

// ---------------- embedding gather ------------------------------------------
__global__ __launch_bounds__(256) void k_gather(const int* __restrict__ toks,
                                                const float* __restrict__ emb,
                                                float* __restrict__ x) {
  int T = blockIdx.x * 256 + threadIdx.x;
  int row = T >> 6, lane = T & 63;
  int tok = toks[row] & (VOCAB - 1);
  const float4* s = (const float4*)(emb + (size_t)tok * D) + lane * 2;
  float4* d = (float4*)(x + (size_t)row * D) + lane * 2;
  d[0] = s[0];
  d[1] = s[1];
}

// ---------------- W (L,512,1024) fp32 -> Wtrow (L,1024,512) bf16 -------------
__global__ __launch_bounds__(256) void k_convW(const float* __restrict__ W,
                                               unsigned short* __restrict__ Wt) {
  __shared__ float tile[32][33];
  int bid = blockIdx.x;
  int l = bid >> 9;
  int rem = bid & 511;
  int kt = rem >> 5, nt = rem & 31;
  int k0 = kt * 32, n0 = nt * 32;
  int tx = threadIdx.x & 31, ty = threadIdx.x >> 5;   // 32 x 8
  const float* Wl = W + (size_t)l * D * 2 * D;
  for (int i = 0; i < 4; i++) {
    int k = k0 + ty + 8 * i;
    tile[ty + 8 * i][tx] = Wl[(size_t)k * 1024 + n0 + tx];
  }
  __syncthreads();
  unsigned short* Wtl = Wt + (size_t)l * 1024 * D;
  for (int i = 0; i < 4; i++) {
    int n = n0 + ty + 8 * i;
    Wtl[(size_t)n * D + k0 + tx] = f2bf(tile[tx][ty + 8 * i]);
  }
}

// ---------------- Wtrow -> B-fragment-ordered WtF ----------------------------
// WtF[l][(n16*16+kt)*64 + lane][e] = Wtrow[l][n16*16 + (lane&15)][kt*32 + (lane>>4)*8 + e]
__global__ __launch_bounds__(256) void k_fragW(const unsigned short* __restrict__ Wt,
                                               unsigned short* __restrict__ WtF) {
  int t = blockIdx.x * 256 + threadIdx.x;
  int lane = t & 63;
  int tile = t >> 6;                 // 0 .. 12*1024-1
  int l = tile >> 10;
  int rem = tile & 1023;
  int n16 = rem >> 4, kt = rem & 15;
  const unsigned short* src = Wt + (size_t)l * 1024 * 512 +
                              (size_t)(n16 * 16 + (lane & 15)) * 512 + kt * 32 + (lane >> 4) * 8;
  unsigned short* dst = WtF + (size_t)l * 1024 * 512 + ((size_t)tile * 64 + lane) * 8 -
                        (size_t)l * 1024 * 512 + (size_t)l * 1024 * 512;  // same layer stride
  *(uint4*)(WtF + (size_t)l * 524288 + ((size_t)rem * 64 + lane) * 8) = *(const uint4*)src;
  (void)dst;
}

// ---------------- emb fp32 -> bf16 (row-major, for logits GEMM) --------------
__global__ __launch_bounds__(256) void k_convEmb(const float* __restrict__ e,
                                                 unsigned short* __restrict__ o) {
  int t = blockIdx.x * 256 + threadIdx.x;
  const float4* s = (const float4*)e + (size_t)t * 2;
  float4 a = s[0], b = s[1];
  uint32_t w0 = (uint32_t)f2bf(a.x) | ((uint32_t)f2bf(a.y) << 16);
  uint32_t w1 = (uint32_t)f2bf(a.z) | ((uint32_t)f2bf(a.w) << 16);
  uint32_t w2 = (uint32_t)f2bf(b.x) | ((uint32_t)f2bf(b.y) << 16);
  uint32_t w3 = (uint32_t)f2bf(b.z) | ((uint32_t)f2bf(b.w) << 16);
  uint4 r; r.x = w0; r.y = w1; r.z = w2; r.w = w3;
  ((uint4*)o)[t] = r;
}

// ---------------- LayerNorm fp32 -> bf16, one wave per row -------------------
__global__ __launch_bounds__(256) void k_ln(const float* __restrict__ x,
                                            const float* __restrict__ g,
                                            const float* __restrict__ b,
                                            unsigned short* __restrict__ o) {
  int wv = threadIdx.x >> 6, lane = threadIdx.x & 63;
  size_t row = (size_t)blockIdx.x * 4 + wv;
  const float4* xr = (const float4*)(x + row * D) + lane * 2;
  float4 v0 = xr[0], v1 = xr[1];
  float s = v0.x + v0.y + v0.z + v0.w + v1.x + v1.y + v1.z + v1.w;
  float ss = v0.x * v0.x + v0.y * v0.y + v0.z * v0.z + v0.w * v0.w +
             v1.x * v1.x + v1.y * v1.y + v1.z * v1.z + v1.w * v1.w;
  for (int m = 32; m; m >>= 1) {
    s += __shfl_xor(s, m, 64);
    ss += __shfl_xor(ss, m, 64);
  }
  float mu = s * (1.0f / 512.0f);
  float var = ss * (1.0f / 512.0f) - mu * mu;
  float rstd = rsqrtf(var + 1e-5f);
  const float4* gp = (const float4*)g + lane * 2;
  const float4* bp = (const float4*)b + lane * 2;
  float4 g0 = gp[0], g1 = gp[1], b0 = bp[0], b1 = bp[1];
  uint32_t w0 = (uint32_t)f2bf((v0.x - mu) * rstd * g0.x + b0.x) |
                ((uint32_t)f2bf((v0.y - mu) * rstd * g0.y + b0.y) << 16);
  uint32_t w1 = (uint32_t)f2bf((v0.z - mu) * rstd * g0.z + b0.z) |
                ((uint32_t)f2bf((v0.w - mu) * rstd * g0.w + b0.w) << 16);
  uint32_t w2 = (uint32_t)f2bf((v1.x - mu) * rstd * g1.x + b1.x) |
                ((uint32_t)f2bf((v1.y - mu) * rstd * g1.y + b1.y) << 16);
  uint32_t w3 = (uint32_t)f2bf((v1.z - mu) * rstd * g1.z + b1.z) |
                ((uint32_t)f2bf((v1.w - mu) * rstd * g1.w + b1.w) << 16);
  uint4 r; r.x = w0; r.y = w1; r.z = w2; r.w = w3;
  ((uint4*)(o + row * D))[lane] = r;
}

// ---------------- mega GEMM + activation + chunk-scan summary ----------------
// Block = 64 rows (one scan chunk) x all 512 d (h and g cols).
// A (64x512) staged once in LDS (swizzled); B loaded per-frag from L2 (WtF is
// pre-ordered in MFMA B-fragment layout). Zero barriers in the K-loop.
// Epilogue: f=sigma(-g), v=sigma(g)*gfun(h) -> packed fp16 fv; and the
// per-chunk (P,Q) scan summary composed in-register (replaces k_scan1).
__global__ __launch_bounds__(256, 2) void k_gemm_act(const unsigned short* __restrict__ A,
                                                     const unsigned short* __restrict__ Bt,
                                                     uint32_t* __restrict__ fv,
                                                     float* __restrict__ P,
                                                     float* __restrict__ Q) {
  __shared__ __align__(16) unsigned short As[64 * 512];   // 64 KiB
  const int tid = threadIdx.x;
  const int lane = tid & 63;
  const int wave = tid >> 6;
  const int m0 = blockIdx.x * 64;
  const int qm = lane & 15;
  const int hi = lane >> 4;          // 0..3
  // ---- stage A: one row per inst, chunk-swizzled (cl = cg&~7 | (cg&7)^(r&7))
  for (int j = 0; j < 16; j++) {
    int r = wave * 16 + j;
    int cg = (lane & ~7) | ((lane & 7) ^ (r & 7));
    gl_lds16(A + (size_t)(m0 + r) * 512 + cg * 8, As + r * 512);
  }
  __syncthreads();

  const int b_loc = m0 >> 13;              // batch within group
  const int c_chunk = (m0 & (SS - 1)) >> 6;
  const size_t pq0 = ((size_t)b_loc * CH + c_chunk) * 512;

  for (int np = 0; np < 2; np++) {
    const int c0 = np * 256 + wave * 64;   // hidden col base for this wave
    const int n16h = (c0 >> 4);            // + j ; gate = +32
    f32x4 ah[4][4] = {};
    f32x4 ag[4][4] = {};
    bf16x8 bh[2][4], bg[2][4];
    for (int j = 0; j < 4; j++) {
      bh[0][j] = *(const bf16x8*)(Bt + (((size_t)(n16h + j) * 16 + 0) * 64 + lane) * 8);
      bg[0][j] = *(const bf16x8*)(Bt + (((size_t)(n16h + j + 32) * 16 + 0) * 64 + lane) * 8);
    }
    for (int kt = 0; kt < 16; kt++) {
      const int cur = kt & 1;
      if (kt < 15) {
        const int nxt = cur ^ 1;
        for (int j = 0; j < 4; j++) {
          bh[nxt][j] = *(const bf16x8*)(Bt + (((size_t)(n16h + j) * 16 + kt + 1) * 64 + lane) * 8);
          bg[nxt][j] = *(const bf16x8*)(Bt + (((size_t)(n16h + j + 32) * 16 + kt + 1) * 64 + lane) * 8);
        }
      }
      bf16x8 af[4];
      for (int i = 0; i < 4; i++) {
        int row = i * 16 + qm;
        int cgd = kt * 4 + hi;
        int cl = (cgd & ~7) | ((cgd & 7) ^ (row & 7));
        af[i] = *(const bf16x8*)(&As[row * 512 + cl * 8]);
      }
      for (int i = 0; i < 4; i++)
        for (int j = 0; j < 4; j++) {
          ah[i][j] = __builtin_amdgcn_mfma_f32_16x16x32_bf16(af[i], bh[cur][j], ah[i][j], 0, 0, 0);
          ag[i][j] = __builtin_amdgcn_mfma_f32_16x16x32_bf16(af[i], bg[cur][j], ag[i][j], 0, 0, 0);
        }
    }
    // ---- epilogue: activation + fv store + (P,Q) chunk summary
    const int rq = hi * 4;
    for (int j = 0; j < 4; j++) {
      float cp = 1.f, cq = 0.f;
      for (int i = 0; i < 4; i++) {
        float sp = 1.f, sq = 0.f;
        for (int r = 0; r < 4; r++) {
          float h = ah[i][j][r];
          float g = ag[i][j][r];
          float e = __expf(g);
          float f = rcpf_(1.0f + e);
          float sg = 1.0f - f;
          float gf = h >= 0.0f ? h + 0.5f : rcpf_(1.0f + __expf(-h));
          float v = sg * gf;
          int rowg = m0 + i * 16 + rq + r;
          fv[(size_t)rowg * 512 + c0 + j * 16 + qm] = pack_fv(f, v);
          sp *= f;
          sq = sq * f + v;
        }
        // ordered combine across hi groups (rows i*16 + hi*4 + r)
        float op = __shfl_xor(sp, 16), oq = __shfl_xor(sq, 16);
        float tp = sp * op;
        float tq = (lane & 16) ? (oq * sp + sq) : (sq * op + oq);
        op = __shfl_xor(tp, 32); oq = __shfl_xor(tq, 32);
        sp = tp * op;
        sq = (lane & 32) ? (oq * tp + tq) : (tq * op + oq);
        // compose chunk (i ascending = row ascending)
        cq = cq * sp + sq;
        cp = cp * sp;
      }
      if (hi == 0) {
        P[pq0 + c0 + j * 16 + qm] = cp;
        Q[pq0 + c0 + j * 16 + qm] = cq;
      }
    }
  }
}

// ---------------- logits GEMM (round-5 structure): C = A * Bt^T --------------
__global__ __launch_bounds__(256) void k_gemm(const unsigned short* __restrict__ A,
                                              const unsigned short* __restrict__ Bt,
                                              float* __restrict__ C, int N, int MT) {
  __shared__ __align__(16) unsigned short As[128 * 64];
  __shared__ __align__(16) unsigned short Bs[128 * 64];
  const int tid = threadIdx.x;
  const int lane = tid & 63;
  const int wave = tid >> 6;
  const int bid = blockIdx.x;
  const int mt = bid % MT;
  const int nt = bid / MT;
  const int m0 = mt * 128, n0 = nt * 128;
  const int wr = (wave >> 1) * 64;
  const int wc = (wave & 1) * 64;
  const int lrow = lane >> 3;
  const int lcs = ((lane & 7) ^ lrow) * 8;
  const unsigned short* Ag = A + (size_t)(m0 + wave * 32 + lrow) * 512 + lcs;
  const unsigned short* Bg = Bt + (size_t)(n0 + wave * 32 + lrow) * 512 + lcs;
  unsigned short* Al = As + wave * 32 * 64;
  unsigned short* Bl = Bs + wave * 32 * 64;
  const int qm = lane & 15;
  const int hi = lane >> 4;
  f32x4 acc[4][4] = {};
  for (int k0 = 0; k0 < 512; k0 += 64) {
    for (int j = 0; j < 4; j++) gl_lds16(Ag + k0 + (size_t)j * 8 * 512, Al + j * 512);
    for (int j = 0; j < 4; j++) gl_lds16(Bg + k0 + (size_t)j * 8 * 512, Bl + j * 512);
    __syncthreads();
    for (int ks = 0; ks < 2; ks++) {
      const int sw = ((ks * 4 + hi) ^ (qm & 7)) * 8;
      bf16x8 af[4], bfr[4];
      for (int i = 0; i < 4; i++) {
        af[i] = *(const bf16x8*)(&As[(wr + i * 16 + qm) * 64 + sw]);
        bfr[i] = *(const bf16x8*)(&Bs[(wc + i * 16 + qm) * 64 + sw]);
      }
      for (int i = 0; i < 4; i++)
        for (int j = 0; j < 4; j++)
          acc[i][j] = __builtin_amdgcn_mfma_f32_16x16x32_bf16(af[i], bfr[j], acc[i][j], 0, 0, 0);
    }
    __syncthreads();
  }
  const int col = lane & 15;
  const int rq = (lane >> 4) * 4;
  for (int i = 0; i < 4; i++)
    for (int j = 0; j < 4; j++)
      for (int r = 0; r < 4; r++)
        C[(size_t)(m0 + wr + i * 16 + rq + r) * N + (n0 + wc + j * 16 + col)] = acc[i][j][r];
}

// ---------------- scan phase 2: prefix over CH chunks per (b,d) --------------
__global__ __launch_bounds__(256) void k_scan2(const float* __restrict__ P,
                                               const float* __restrict__ Q,
                                               float* __restrict__ Hs) {
  int T = blockIdx.x * 256 + threadIdx.x;  // b*512 + d
  int d = T & 511;
  int b = T >> 9;
  float h = 0.f;
  for (int c = 0; c < CH; c++) {
    size_t i = ((size_t)b * CH + c) * 512 + d;
    Hs[i] = h;
    h = P[i] * h + Q[i];
  }
}

// ---------------- scan phase 3: apply + residual add into x ------------------
__global__ __launch_bounds__(256) void k_scan3(const uint32_t* __restrict__ fv,
                                               const float* __restrict__ Hs,
                                               float* __restrict__ x) {
  int T = blockIdx.x * 256 + threadIdx.x;
  int d = T & 511;
  int bc = T >> 9;
  int c = bc & (CH - 1);
  int b = bc >> 7;
  const uint32_t* base = fv + ((size_t)b * SS + c * SL) * 512 + d;
  float* xb = x + ((size_t)b * SS + c * SL) * 512 + d;
  float h = Hs[T];
  for (int s = 0; s < SL; s++) {
    float f, v;
    unpack_fv(base[(size_t)s * 512], f, v);
    h = f * h + v;
    xb[(size_t)s * 512] += h;
  }
}

extern "C" void kernel_launch(void* const* d_in, const int* in_sizes, int n_in,
                              void* d_out, int out_size, void* d_ws, size_t ws_size,
                              hipStream_t stream) {
  const int* toks = (const int*)d_in[0];
  const float* emb = (const float*)d_in[1];
  const float* ln_g = (const float*)d_in[2];
  const float* ln_b = (const float*)d_in[3];
  const float* W = (const float*)d_in[4];
  const float* norm_g = (const float*)d_in[5];
  const float* norm_b = (const float*)d_in[6];
  float* out = (float*)d_out;   // fp32 logits

  // Batch-group ladder; ws_size constant across calls -> graph-safe.
  const int gbs[4] = {8, 4, 2, 1};
  int GB = 1;
  for (int i = 0; i < 4; i++) {
    size_t MGv = (size_t)gbs[i] * SS;
    size_t need = MGv * 5120 + 2 * 12582912 + 262144 + (size_t)gbs[i] * 786432;
    if (need <= ws_size) { GB = gbs[i]; break; }
  }
  const int MG = GB * SS;        // rows per group
  const int MT128 = MG / 128;    // 128-row m-tiles (logits gemm)

  char* p = (char*)d_ws;
  float* x = (float*)p;                     p += (size_t)MG * 2048;
  uint32_t* fv = (uint32_t*)p;              p += (size_t)MG * 2048;
  unsigned short* hbf = (unsigned short*)p; p += (size_t)MG * 1024;
  unsigned short* Wtrow = (unsigned short*)p; p += 12582912;
  unsigned short* WtF = (unsigned short*)p;   p += 12582912;
  unsigned short* ebf = (unsigned short*)p;   p += 262144;
  float* P = (float*)p;                     p += (size_t)GB * 262144;
  float* Q = (float*)p;                     p += (size_t)GB * 262144;
  float* Hs = (float*)p;

  k_convW<<<NLAYER * 512, 256, 0, stream>>>(W, Wtrow);
  k_fragW<<<NLAYER * 1024 * 64 / 256, 256, 0, stream>>>(Wtrow, WtF);
  k_convEmb<<<64, 256, 0, stream>>>(emb, ebf);

  for (int g = 0; g < BB / GB; g++) {
    const int* tg = toks + (size_t)g * MG;
    float* outg = out + (size_t)g * MG * VOCAB;

    k_gather<<<MG / 4, 256, 0, stream>>>(tg, emb, x);
    for (int l = 0; l < NLAYER; l++) {
      k_ln<<<MG / 4, 256, 0, stream>>>(x, ln_g + l * D, ln_b + l * D, hbf);
      k_gemm_act<<<MG / 64, 256, 0, stream>>>(hbf, WtF + (size_t)l * 524288, fv, P, Q);
      k_scan2<<<GB * 2, 256, 0, stream>>>(P, Q, Hs);
      k_scan3<<<GB * CH * 2, 256, 0, stream>>>(fv, Hs, x);
    }
    k_ln<<<MG / 4, 256, 0, stream>>>(x, norm_g, norm_b, hbf);
    k_gemm<<<2 * MT128, 256, 0, stream>>>(hbf, ebf, outg, VOCAB, MT128);
  }
}